// Round 1
// 491.307 us; speedup vs baseline: 1.0690x; 1.0690x over previous
//
#include <hip/hip_runtime.h>
#include <hip/hip_bf16.h>
#include <math.h>

typedef __attribute__((ext_vector_type(8))) short bf16x8;
typedef __attribute__((ext_vector_type(4))) float f32x4;

#define B_ 8192
#define F_ 26
#define D_ 32
#define V_ 100000

// ---- ws layout (bytes), 16B-aligned ----
static const size_t OFF_VB   = 0;             // bf16 8192x832  = 13631488
static const size_t OFF_FD0  = 13631488;      // f32 8192       = 32768  (lin+cin dot)
static const size_t OFF_PDH2 = 13664256;      // f32 4x8192     = 131072 (h2 col-chunk partial dots)
static const size_t OFF_H1B  = 13795328;      // bf16 8192x400  = 6553600
static const size_t OFF_W1T  = 20348928;      // bf16 400x832   = 665600
static const size_t OFF_W2T  = 21014528;      // bf16 400x400   = 320000
static const size_t OFF_MTF  = 21334528;      // f32 32x128     = 16384  (M[i][j]; row26=wout1; rows27..31=0)
static const size_t OFF_K2T  = 21350912;      // bf16 2x352x32  = 45056  (hi plane, lo plane)
// total ~21.4 MB

// RNE bf16 (weights, one-time)
static __device__ __forceinline__ unsigned short f2b(float f) {
    unsigned int u = __float_as_uint(f);
    return (unsigned short)((u + 0x7FFF + ((u >> 16) & 1)) >> 16);
}
// truncating bf16 (activations)
static __device__ __forceinline__ unsigned short f2bt(float f) {
    return (unsigned short)(__float_as_uint(f) >> 16);
}
// pack two truncated bf16 in one v_perm_b32
static __device__ __forceinline__ unsigned int pk2t(float a, float b) {
    return __builtin_amdgcn_perm(__float_as_uint(b), __float_as_uint(a), 0x07060302u);
}
static __device__ __forceinline__ float bf2f(unsigned short u) {
    return __uint_as_float(((unsigned int)u) << 16);
}

// ======== K0a: W1/W2 transposes + M matrix ========
static __device__ __forceinline__ void transpose_body(
    const float* __restrict__ src, unsigned short* __restrict__ dst,
    int K, int N, int bx, int by)
{
    __shared__ float tl[32][33];
    const int lx = threadIdx.x & 31, ly = threadIdx.x >> 5;
    const int n0 = bx * 32, k0 = by * 32;
#pragma unroll
    for (int i = 0; i < 4; ++i) {
        int k = k0 + ly + i * 8, n = n0 + lx;
        if (k < K && n < N) tl[ly + i * 8][lx] = src[(size_t)k * N + n];
    }
    __syncthreads();
#pragma unroll
    for (int i = 0; i < 4; ++i) {
        int n = n0 + ly + i * 8, k = k0 + lx;
        if (k < K && n < N) dst[(size_t)n * K + k] = f2b(tl[lx][ly + i * 8]);
    }
}

__global__ __launch_bounds__(256) void k0a(
    const float* __restrict__ W1, const float* __restrict__ W2,
    const float* __restrict__ Wc1, const float* __restrict__ wout,
    unsigned short* __restrict__ W1t, unsigned short* __restrict__ W2t,
    float* __restrict__ MtF)
{
    __shared__ float w2s[128];
    int bid = blockIdx.x;
    if (bid < 338) { transpose_body(W1, W1t, 832, 400, bid % 13, bid / 13); return; }
    bid -= 338;
    if (bid < 169) { transpose_body(W2, W2t, 400, 400, bid % 13, bid / 13); return; }
    bid -= 169;
    // MtF[i][j] (32x128): i<26: sum_h Wc1[i][j][h]*wout[129+h]; i==26: wout[1+j]; i>26: 0
    if (threadIdx.x < 128) w2s[threadIdx.x] = wout[129 + threadIdx.x];
    __syncthreads();
    int g = bid * 256 + threadIdx.x;      // 0..4095
    int i = g >> 7, j = g & 127;
    float s = 0.f;
    if (i < F_) {
        const float* row = Wc1 + ((size_t)i * 128 + j) * 128;
        for (int h = 0; h < 128; h += 4) {
            float4 a = *(const float4*)(row + h);
            s = fmaf(a.x, w2s[h], s);
            s = fmaf(a.y, w2s[h + 1], s);
            s = fmaf(a.z, w2s[h + 2], s);
            s = fmaf(a.w, w2s[h + 3], s);
        }
    } else if (i == F_) {
        s = wout[1 + j];
    }
    MtF[g] = s;
}

// ======== K0b: K2T[q][i] = sum_j W0sym[q,j] * MtF[i][j], bf16 hi/lo split ========
__global__ __launch_bounds__(256) void k0b(
    const float* __restrict__ W0, const float* __restrict__ MtF,
    unsigned short* __restrict__ K2T)
{
    int g = blockIdx.x * 256 + threadIdx.x;    // 0..11263
    int q = g >> 5, i = g & 31;
    float s = 0.f;
    if (q < 351) {
        int a = 0, base = 0;
        while (base + (F_ - a) <= q) { base += F_ - a; ++a; }
        int b = a + (q - base);
        const float* r0 = W0 + ((size_t)a * F_ + b) * 128;
        const float* r1 = W0 + ((size_t)b * F_ + a) * 128;
        const float* m  = MtF + (size_t)i * 128;
        if (a == b) {
            for (int j = 0; j < 128; j += 4) {
                float4 w = *(const float4*)(r0 + j);
                float4 mm = *(const float4*)(m + j);
                s += w.x * mm.x + w.y * mm.y + w.z * mm.z + w.w * mm.w;
            }
        } else {
            for (int j = 0; j < 128; j += 4) {
                float4 w = *(const float4*)(r0 + j);
                float4 w1 = *(const float4*)(r1 + j);
                float4 mm = *(const float4*)(m + j);
                s += (w.x + w1.x) * mm.x + (w.y + w1.y) * mm.y
                   + (w.z + w1.z) * mm.z + (w.w + w1.w) * mm.w;
            }
        }
    }
    unsigned short hi = f2b(s);
    float lo = s - bf2f(hi);
    K2T[g] = hi;                 // hi plane [352][32]
    K2T[11264 + g] = f2b(lo);    // lo plane
}

// ======== K1: one b per block: gather + Ht MFMA + in-register pe dot ========
__global__ __launch_bounds__(256) void k1_embed_cin(
    const int*   __restrict__ sparse,
    const float* __restrict__ E,
    const unsigned short* __restrict__ K2T,
    const float* __restrict__ wlin,
    const float* __restrict__ blin,
    const float* __restrict__ wout,
    unsigned short* __restrict__ vb,
    float* __restrict__ fdot0)
{
    __shared__ __align__(16) unsigned short embT[32][40];  // [d][i]; col26=1.0, 27..31=0
    __shared__ unsigned int PQ[352];                        // i | (j<<16)
    __shared__ int idxs[F_];
    __shared__ float red[4];

    const int b = blockIdx.x, t = threadIdx.x;
    float cind = 0.f;

    if (t < F_) {
        int id = sparse[b * F_ + t];
        idxs[t] = id;
        cind = (float)id * wlin[t] * wout[0];          // lin folded into the block dot
        int base = F_ * t - (t * (t - 1)) / 2;
        for (int j = t; j < F_; ++j)
            PQ[base + j - t] = (unsigned)t | ((unsigned)j << 16);
    }
    if (t == F_) PQ[351] = 0u;                          // pad row (K2T row 351 is zero)
    if (t >= 32 && t < 64) {                            // ones col + zero pad cols
        int d = t - 32;
        embT[d][26] = 0x3F80;                           // bf16 1.0
        embT[d][27] = 0; embT[d][28] = 0; embT[d][29] = 0;
        embT[d][30] = 0; embT[d][31] = 0;
    }
    __syncthreads();

    // gather 26 rows x 8 float4 -> vb (global, bf16) + embT (transposed LDS)
    if (t < 208) {
        int f = t >> 3, q = t & 7;
        float4 v4 = *(const float4*)(E + ((size_t)f * V_ + idxs[f]) * D_ + q * 4);
        uint2 uu; uu.x = pk2t(v4.x, v4.y); uu.y = pk2t(v4.z, v4.w);
        *(uint2*)(vb + (size_t)b * 832 + f * 32 + q * 4) = uu;
        embT[q * 4 + 0][f] = f2bt(v4.x);
        embT[q * 4 + 1][f] = f2bt(v4.y);
        embT[q * 4 + 2][f] = f2bt(v4.z);
        embT[q * 4 + 3][f] = f2bt(v4.w);
    }
    __syncthreads();

    // Ht[d][q] = sum_i embT[d][i]*K2[q][i] via MFMA; dot vs pe[q,d]=emb_i[d]*emb_j[d]
    const int wave = t >> 6, lane = t & 63;
    const int lr = lane & 15, lg = lane >> 4;
    const int mt = wave & 1;            // m-tile (d-half) fixed per wave
    const int nb = wave >> 1;           // nt = 2*s + nb
    bf16x8 af = *(const bf16x8*)&embT[mt * 16 + lr][lg * 8];
    const unsigned short* ebase = &embT[mt * 16 + lg * 4][0];
    const unsigned short* Kb = K2T + (size_t)lr * 32 + lg * 8;

#pragma unroll
    for (int s = 0; s < 11; ++s) {
        const int nt = 2 * s + nb;
        bf16x8 bh = *(const bf16x8*)(Kb + (size_t)nt * 512);
        bf16x8 bl = *(const bf16x8*)(Kb + 11264 + (size_t)nt * 512);
        f32x4 h = {};
        h = __builtin_amdgcn_mfma_f32_16x16x32_bf16(af, bl, h, 0, 0, 0);
        h = __builtin_amdgcn_mfma_f32_16x16x32_bf16(af, bh, h, 0, 0, 0);
        unsigned pq = PQ[nt * 16 + lr];
        int oi = (int)(pq & 0xFFFFu), oj = (int)(pq >> 16);
#pragma unroll
        for (int r = 0; r < 4; ++r) {
            float ei = bf2f(ebase[r * 40 + oi]);
            float ej = bf2f(ebase[r * 40 + oj]);
            cind = fmaf(ei * ej, h[r], cind);
        }
    }

#pragma unroll
    for (int off = 1; off <= 32; off <<= 1) cind += __shfl_xor(cind, off, 64);
    if (lane == 0) red[wave] = cind;
    __syncthreads();
    if (t == 0) fdot0[b] = red[0] + red[1] + red[2] + red[3] + blin[0] * wout[0];
}

// ======== GEMM core: 64x128 tile, BK=32, reg prefetch ========
static __device__ __forceinline__ void gemm_core(
    const unsigned short* __restrict__ A, int lda,
    const unsigned short* __restrict__ Bt, int ldb, int N,
    int m0, int n0, int kbase, int kend,
    unsigned short (*As)[40], unsigned short (*Bs)[40],
    f32x4 (*acc)[2])
{
    const int t = threadIdx.x;
    const int wave = t >> 6, lane = t & 63;
    const int lr = lane & 15, lg = lane >> 4;
    const int wn = wave * 32;
    const int ar = t >> 2, kg = (t & 3) * 8;

    const unsigned short* aptr = A  + (size_t)(m0 + ar) * lda + kbase + kg;
    const unsigned short* bp0  = Bt + (size_t)(n0 + ar) * ldb + kbase + kg;
    const unsigned short* bp1  = Bt + (size_t)(n0 + 64 + ar) * ldb + kbase + kg;
    const bool bn0 = (n0 + ar) < N, bn1 = (n0 + 64 + ar) < N;
    const uint4 z4 = make_uint4(0u, 0u, 0u, 0u);
    const int nkt = (kend - kbase + 31) >> 5;
    uint4 av, bv0, bv1;
    {
        int k = kbase + kg;
        av  = (k < kend)        ? *(const uint4*)aptr : z4;
        bv0 = (bn0 && k < kend) ? *(const uint4*)bp0  : z4;
        bv1 = (bn1 && k < kend) ? *(const uint4*)bp1  : z4;
    }
    for (int kt = 0; kt < nkt; ++kt) {
        *(uint4*)&As[ar][kg]      = av;
        *(uint4*)&Bs[ar][kg]      = bv0;
        *(uint4*)&Bs[64 + ar][kg] = bv1;
        __syncthreads();
        if (kt + 1 < nkt) {
            int kn = kbase + (kt + 1) * 32 + kg;
            av  = (kn < kend)        ? *(const uint4*)(aptr + (kt + 1) * 32) : z4;
            bv0 = (bn0 && kn < kend) ? *(const uint4*)(bp0  + (kt + 1) * 32) : z4;
            bv1 = (bn1 && kn < kend) ? *(const uint4*)(bp1  + (kt + 1) * 32) : z4;
        }
        bf16x8 af[4], bfr[2];
#pragma unroll
        for (int i = 0; i < 4; ++i) af[i]  = *(const bf16x8*)&As[i * 16 + lr][lg * 8];
#pragma unroll
        for (int j = 0; j < 2; ++j) bfr[j] = *(const bf16x8*)&Bs[wn + j * 16 + lr][lg * 8];
#pragma unroll
        for (int i = 0; i < 4; ++i)
#pragma unroll
            for (int j = 0; j < 2; ++j)
                acc[i][j] = __builtin_amdgcn_mfma_f32_16x16x32_bf16(af[i], bfr[j], acc[i][j], 0, 0, 0);
        __syncthreads();
    }
}

// K2a: h1 = relu(vb@W1+b1) (bf16 out)
__global__ __launch_bounds__(256) void k2_h1(
    const unsigned short* __restrict__ vb, const unsigned short* __restrict__ W1t,
    const float* __restrict__ b1, unsigned short* __restrict__ h1b)
{
    __shared__ __align__(16) unsigned short As[64][40];
    __shared__ __align__(16) unsigned short Bs[128][40];
    const int t = threadIdx.x;
    const int wave = t >> 6, lane = t & 63;
    const int lr = lane & 15, lg = lane >> 4;
    const int m0 = blockIdx.y * 64, n0 = blockIdx.x * 128;
    f32x4 acc[4][2] = {};
    gemm_core(vb, 832, W1t, 832, 400, m0, n0, 0, 832, As, Bs, acc);
#pragma unroll
    for (int i = 0; i < 4; ++i) {
        int mrow = m0 + i * 16 + lg * 4;
#pragma unroll
        for (int j = 0; j < 2; ++j) {
            int col = n0 + wave * 32 + j * 16 + lr;
            if (col >= 400) continue;
            float bb = b1[col];
#pragma unroll
            for (int r = 0; r < 4; ++r)
                h1b[(size_t)(mrow + r) * 400 + col] = f2bt(fmaxf(acc[i][j][r] + bb, 0.f));
        }
    }
}

// K2b: h2 never materialized — bias+relu+dot(wout) -> pdh2[nb][b]
__global__ __launch_bounds__(256) void k2_h2(
    const unsigned short* __restrict__ h1b, const unsigned short* __restrict__ W2t,
    const float* __restrict__ b2, const float* __restrict__ wout,
    float* __restrict__ pdh2)
{
    __shared__ __align__(16) unsigned short As[64][40];
    __shared__ __align__(16) unsigned short Bs[128][40];
    __shared__ float red[4][64];
    const int t = threadIdx.x;
    const int wave = t >> 6, lane = t & 63;
    const int lr = lane & 15, lg = lane >> 4;
    const int m0 = blockIdx.y * 64, n0 = blockIdx.x * 128;
    f32x4 acc[4][2] = {};
    gemm_core(h1b, 400, W2t, 400, 400, m0, n0, 0, 400, As, Bs, acc);
    float v[4][4];
#pragma unroll
    for (int i = 0; i < 4; ++i)
#pragma unroll
        for (int r = 0; r < 4; ++r) {
            float s = 0.f;
#pragma unroll
            for (int j = 0; j < 2; ++j) {
                int col = n0 + wave * 32 + j * 16 + lr;
                if (col < 400)
                    s = fmaf(fmaxf(acc[i][j][r] + b2[col], 0.f), wout[257 + col], s);
            }
#pragma unroll
            for (int off = 1; off <= 8; off <<= 1) s += __shfl_xor(s, off, 64);
            v[i][r] = s;
        }
    if (lr == 0) {
#pragma unroll
        for (int i = 0; i < 4; ++i)
#pragma unroll
            for (int r = 0; r < 4; ++r) red[wave][i * 16 + lg * 4 + r] = v[i][r];
    }
    __syncthreads();
    if (t < 64) pdh2[(size_t)blockIdx.x * B_ + m0 + t] = red[0][t] + red[1][t] + red[2][t] + red[3][t];
}

// ======== K3: sum partials + dense dot + sigmoid ========
__global__ __launch_bounds__(256) void k3_final(
    const float* __restrict__ fdot0,
    const float* __restrict__ pdh2,
    const float* __restrict__ dense,
    const float* __restrict__ wout,
    const float* __restrict__ bout,
    float* __restrict__ out)
{
    const int b = blockIdx.x * 256 + threadIdx.x;
    float s = fdot0[b];
#pragma unroll
    for (int z = 0; z < 4; ++z) s += pdh2[(size_t)z * B_ + b];
#pragma unroll
    for (int q = 0; q < 13; ++q) s = fmaf(dense[(size_t)b * 13 + q], wout[657 + q], s);
    out[b] = 1.f / (1.f + expf(-(s + bout[0])));
}

extern "C" void kernel_launch(void* const* d_in, const int* in_sizes, int n_in,
                              void* d_out, int out_size, void* d_ws, size_t ws_size,
                              hipStream_t stream) {
    const float* dense  = (const float*)d_in[0];
    const int*   sparse = (const int*)  d_in[1];
    const float* E      = (const float*)d_in[2];
    const float* W0     = (const float*)d_in[3];
    const float* Wc1    = (const float*)d_in[4];
    const float* W1     = (const float*)d_in[5];
    const float* b1     = (const float*)d_in[6];
    const float* W2     = (const float*)d_in[7];
    const float* b2     = (const float*)d_in[8];
    const float* wlin   = (const float*)d_in[9];
    const float* blin   = (const float*)d_in[10];
    const float* wout   = (const float*)d_in[11];
    const float* bout   = (const float*)d_in[12];
    float* out = (float*)d_out;

    char* ws = (char*)d_ws;
    unsigned short* vb    = (unsigned short*)(ws + OFF_VB);
    float*          fdot0 = (float*)(ws + OFF_FD0);
    float*          pdh2  = (float*)(ws + OFF_PDH2);
    unsigned short* h1b   = (unsigned short*)(ws + OFF_H1B);
    unsigned short* W1t   = (unsigned short*)(ws + OFF_W1T);
    unsigned short* W2t   = (unsigned short*)(ws + OFF_W2T);
    float*          MtF   = (float*)(ws + OFF_MTF);
    unsigned short* K2T   = (unsigned short*)(ws + OFF_K2T);

    k0a<<<338 + 169 + 16, 256, 0, stream>>>(W1, W2, Wc1, wout, W1t, W2t, MtF);
    k0b<<<44, 256, 0, stream>>>(W0, MtF, K2T);
    k1_embed_cin<<<B_, 256, 0, stream>>>(sparse, E, K2T, wlin, blin, wout, vb, fdot0);
    k2_h1<<<dim3(4, 128), 256, 0, stream>>>(vb, W1t, b1, h1b);
    k2_h2<<<dim3(4, 128), 256, 0, stream>>>(h1b, W2t, b2, wout, pdh2);
    k3_final<<<B_ / 256, 256, 0, stream>>>(fdot0, pdh2, dense, wout, bout, out);
}